// Round 6
// baseline (405.907 us; speedup 1.0000x reference)
//
#include <hip/hip_runtime.h>

typedef unsigned long long u64;
typedef unsigned int u32;

// Workspace layout:
//   [0, 73728)            : packed weight sign words  swg[o][pos][cw]  (9216 u64)
//   [73728, +3211264)     : packed x sign words pk[n][cw][h][w]  (u64, w-contiguous)
#define PK_OFF 73728
#define NO 16  // output channels per block (register-blocked per thread)
#define WP 2   // pixels (w) per thread

// ---------------------------------------------------------------------------
// Kernel 1: decode codebook weights, pack sign bits.
// ---------------------------------------------------------------------------
__global__ __launch_bounds__(256) void pack_w_kernel(const int* __restrict__ enc,
                                                     const float* __restrict__ cb,
                                                     u64* __restrict__ swg) {
    int wid  = blockIdx.x * 4 + (threadIdx.x >> 6);   // 0..9215
    int lane = threadIdx.x & 63;
    int o   = wid / 36;
    int r   = wid - o * 36;
    int pos = r >> 2;
    int cw  = r & 3;
    int i   = (cw << 6) | lane;
    int f   = o * 2304 + i * 9 + pos;
    int j   = f / 12;
    int t   = f - j * 12;
    float val = cb[enc[j] * 12 + t];
    u64 bits = __ballot(val < 0.0f);
    if (lane == 0) swg[wid] = bits;
}

// ---------------------------------------------------------------------------
// Kernel 2: binarize x. Block=(n, h-quad); wave cw covers channels [cw*64,+64).
// Lane l holds 4 consecutive positions of the 224-float (4-row) strip; the
// c-loop does 64 coalesced float4 loads (896B per wave-inst). Each lane
// builds 4 bit-words and stores 32B coalesced.
// Output: pk[n][cw][h][w], w-contiguous.
// ---------------------------------------------------------------------------
__global__ __launch_bounds__(256) void pack_x_kernel(const float* __restrict__ x,
                                                     u64* __restrict__ pk) {
    int nhq  = blockIdx.x;            // n*14 + hq  (grid 448)
    int cw   = threadIdx.x >> 6;
    int lane = threadIdx.x & 63;
    int n    = nhq / 14;
    int hq   = nhq - n * 14;
    int h0   = hq * 4;
    bool act = lane < 56;             // 56*4 = 224 strip positions exactly
    int ll   = act ? lane : 55;       // clamp: idle lanes stay in-bounds
    const float4* xp = (const float4*)(x + ((size_t)(n * 256 + cw * 64)) * 3136
                                         + (size_t)h0 * 56) + ll;
    u32 lo0 = 0, lo1 = 0, lo2 = 0, lo3 = 0;
    u32 hi0 = 0, hi1 = 0, hi2 = 0, hi3 = 0;
#pragma unroll
    for (int c = 0; c < 32; ++c) {
        float4 v = xp[(size_t)c * 784];           // 3136 floats / 4 per channel
        lo0 |= (v.x < 0.0f) ? (1u << c) : 0u;
        lo1 |= (v.y < 0.0f) ? (1u << c) : 0u;
        lo2 |= (v.z < 0.0f) ? (1u << c) : 0u;
        lo3 |= (v.w < 0.0f) ? (1u << c) : 0u;
    }
#pragma unroll
    for (int c = 0; c < 32; ++c) {
        float4 v = xp[(size_t)(c + 32) * 784];
        hi0 |= (v.x < 0.0f) ? (1u << c) : 0u;
        hi1 |= (v.y < 0.0f) ? (1u << c) : 0u;
        hi2 |= (v.z < 0.0f) ? (1u << c) : 0u;
        hi3 |= (v.w < 0.0f) ? (1u << c) : 0u;
    }
    if (act) {
        u64* dst = pk + (((size_t)n * 4 + cw) * 56 + h0) * 56 + 4 * lane;
        ((ulonglong2*)dst)[0] = make_ulonglong2(((u64)hi0 << 32) | lo0,
                                                ((u64)hi1 << 32) | lo1);
        ((ulonglong2*)dst)[1] = make_ulonglong2(((u64)hi2 << 32) | lo2,
                                                ((u64)hi3 << 32) | lo3);
    }
}

// ---------------------------------------------------------------------------
// Kernel 3: popcount conv, 2 pixels x 16 output channels per thread.
// s = 256*nr*nc - 2*(Q - corr). Weights in LDS as ulonglong2 [pos][cw][jj].
// Register pressure management (R2: 256 VGPR spill; R3: cap-64 spill):
//   - launch_bounds(256,2): cap ~128 VGPR
//   - cw loop NOT unrolled: contains live ranges per iteration
// ---------------------------------------------------------------------------
__global__ __launch_bounds__(256, 2) void conv_kernel(const u64* __restrict__ pk,
                                                      const u64* __restrict__ swg,
                                                      float* __restrict__ y) {
    __shared__ ulonglong2 swl2[9 * 4 * 8];   // u64[pos][cw][j], j fastest (16)
    __shared__ int wpl[9 * 16];              // [pos][j] = sum_cw popc(sw)
    u64* swl = (u64*)swl2;
    int tid = threadIdx.x;
    int o0  = blockIdx.y * NO;
    for (int idx = tid; idx < 576; idx += 256) {   // grid-stride staging
        int pos = idx >> 6, rem = idx & 63, cw = rem >> 4, j = rem & 15;
        swl[idx] = swg[(o0 + j) * 36 + pos * 4 + cw];
    }
    if (tid < 144) {
        int pos = tid >> 4, j = tid & 15;
        const u64* p = swg + (o0 + j) * 36 + pos * 4;
        wpl[tid] = __popcll(p[0]) + __popcll(p[1]) + __popcll(p[2]) + __popcll(p[3]);
    }
    __syncthreads();

    int gs = blockIdx.x * 256 + tid;       // 0..50175 (grid.x = 196, exact)
    int n  = gs / 1568;                    // 56*28
    int r2 = gs - n * 1568;
    int h  = r2 / 28;
    int wg = r2 - h * 28;
    int w0 = wg * 2;

    int Q[WP][NO];
#pragma unroll
    for (int p = 0; p < WP; ++p)
#pragma unroll
        for (int j = 0; j < NO; ++j) Q[p][j] = 0;

    const u64* pkn = pk + (size_t)n * 4 * 3136;

#pragma unroll 1
    for (int cw = 0; cw < 4; ++cw) {
#pragma unroll
        for (int r = 0; r < 3; ++r) {
            int hh = h - 1 + r;
            int hc = hh < 0 ? 0 : (hh > 55 ? 55 : hh);
            const u64* rowp = pkn + ((size_t)cw * 56 + hc) * 56;
            bool hv = (hh >= 0) && (hh <= 55);
            u64 win[4];
#pragma unroll
            for (int c4 = 0; c4 < 4; ++c4) {
                int cc  = w0 - 1 + c4;
                int ccc = cc < 0 ? 0 : (cc > 55 ? 55 : cc);
                u64 v   = rowp[ccc];
                bool ok = hv && (cc >= 0) && (cc <= 55);
                win[c4] = ok ? v : 0ull;
            }
#pragma unroll
            for (int dw = 0; dw < 3; ++dw) {
#pragma unroll
                for (int jj = 0; jj < 8; ++jj) {
                    ulonglong2 wv = swl2[((r * 3 + dw) * 4 + cw) * 8 + jj];
                    Q[0][2 * jj]     += __popcll(win[dw]     ^ wv.x);
                    Q[1][2 * jj]     += __popcll(win[dw + 1] ^ wv.x);
                    Q[0][2 * jj + 1] += __popcll(win[dw]     ^ wv.y);
                    Q[1][2 * jj + 1] += __popcll(win[dw + 1] ^ wv.y);
                }
            }
        }
    }

    // Border corrections: subtract popc(sw) of zeroed (invalid) window words.
    if (h == 0 || h == 55 || w0 == 0 || w0 == 54) {
#pragma unroll
        for (int j = 0; j < NO; ++j) {
            int crow = 0;
            if (h == 0)  crow += wpl[0 * 16 + j] + wpl[1 * 16 + j] + wpl[2 * 16 + j];
            if (h == 55) crow += wpl[6 * 16 + j] + wpl[7 * 16 + j] + wpl[8 * 16 + j];
#pragma unroll
            for (int p = 0; p < WP; ++p) {
                int w = w0 + p;
                int c = crow;
                if (w == 0) {
                    if (h > 0)  c += wpl[0 * 16 + j];
                    c += wpl[3 * 16 + j];
                    if (h < 55) c += wpl[6 * 16 + j];
                }
                if (w == 55) {
                    if (h > 0)  c += wpl[2 * 16 + j];
                    c += wpl[5 * 16 + j];
                    if (h < 55) c += wpl[8 * 16 + j];
                }
                Q[p][j] -= c;
            }
        }
    }

    int nr = 3 - (h == 0) - (h == 55);
    int base[WP];
#pragma unroll
    for (int p = 0; p < WP; ++p) {
        int w  = w0 + p;
        int nc = 3 - (w == 0) - (w == 55);
        base[p] = 256 * nr * nc;
    }

    float* yb = y + (size_t)(n * 256 + o0) * 3136 + h * 56 + w0;
#pragma unroll
    for (int j = 0; j < NO; ++j) {
        float2 v;
        v.x = (float)(base[0] - 2 * Q[0][j]);
        v.y = (float)(base[1] - 2 * Q[1][j]);
        *(float2*)(yb + (size_t)j * 3136) = v;
    }
}

extern "C" void kernel_launch(void* const* d_in, const int* in_sizes, int n_in,
                              void* d_out, int out_size, void* d_ws, size_t ws_size,
                              hipStream_t stream) {
    const float* x  = (const float*)d_in[0];
    // d_in[1] (latent weight) is unused in the forward value (STE).
    const float* cb = (const float*)d_in[2];
    const int* enc  = (const int*)d_in[3];
    float* y        = (float*)d_out;

    u64* swg = (u64*)d_ws;
    u64* pk  = (u64*)((char*)d_ws + PK_OFF);

    hipLaunchKernelGGL(pack_w_kernel, dim3(2304), dim3(256), 0, stream, enc, cb, swg);
    hipLaunchKernelGGL(pack_x_kernel, dim3(448), dim3(256), 0, stream, x, pk);
    hipLaunchKernelGGL(conv_kernel, dim3(196, NO), dim3(256), 0, stream, pk, swg, y);
}

// Round 7
// 337.484 us; speedup vs baseline: 1.2027x; 1.2027x over previous
//
#include <hip/hip_runtime.h>

typedef unsigned long long u64;
typedef unsigned int u32;

// Workspace layout:
//   [0, 73728)            : packed weight sign words  swg[o][pos][cw]  (9216 u64)
//   [73728, +3211264)     : packed x sign words pk[n][cw][h][w]  (u64, w-contiguous)
#define PK_OFF 73728
#define NO 8   // output channels per block. R2/R5 lesson: NO=16 or WP=4 -> spill.
#define WP 2   // pixels (w) per thread

// ---------------------------------------------------------------------------
// Kernel 1: decode codebook weights, pack sign bits.
// ---------------------------------------------------------------------------
__global__ __launch_bounds__(256) void pack_w_kernel(const int* __restrict__ enc,
                                                     const float* __restrict__ cb,
                                                     u64* __restrict__ swg) {
    int wid  = blockIdx.x * 4 + (threadIdx.x >> 6);   // 0..9215
    int lane = threadIdx.x & 63;
    int o   = wid / 36;
    int r   = wid - o * 36;
    int pos = r >> 2;
    int cw  = r & 3;
    int i   = (cw << 6) | lane;
    int f   = o * 2304 + i * 9 + pos;
    int j   = f / 12;
    int t   = f - j * 12;
    float val = cb[enc[j] * 12 + t];
    u64 bits = __ballot(val < 0.0f);
    if (lane == 0) swg[wid] = bits;
}

// ---------------------------------------------------------------------------
// Kernel 2: binarize x. Block=(n,h) -> grid 1792 (28 waves/CU: R5's 448-block
// version had ~1.75 waves/SIMD -> latency-bound). Wave cw covers channels
// [cw*64,+64); lane = w. Scalar float loads, 224B coalesced per wave-inst;
// unroll 4 keeps a few loads in flight at low VGPR cost.
// Output: pk[n][cw][h][w], w-contiguous.
// ---------------------------------------------------------------------------
__global__ __launch_bounds__(256) void pack_x_kernel(const float* __restrict__ x,
                                                     u64* __restrict__ pk) {
    int nh   = blockIdx.x;            // n*56 + h  (grid 1792)
    int cw   = threadIdx.x >> 6;
    int lane = threadIdx.x & 63;
    int n    = nh / 56;
    int h    = nh - n * 56;
    int lw   = lane < 56 ? lane : 55; // clamp: lanes 56-63 idle, stay in-bounds
    const float* xp = x + ((size_t)(n * 256 + cw * 64)) * 3136 + (size_t)h * 56 + lw;
    u32 lo = 0, hi = 0;
#pragma unroll 4
    for (int c = 0; c < 32; ++c) {
        float v = xp[(size_t)c * 3136];
        lo |= (v < 0.0f) ? (1u << c) : 0u;
    }
#pragma unroll 4
    for (int c = 0; c < 32; ++c) {
        float v = xp[(size_t)(c + 32) * 3136];
        hi |= (v < 0.0f) ? (1u << c) : 0u;
    }
    if (lane < 56)
        pk[(((size_t)n * 4 + cw) * 56 + h) * 56 + lane] = ((u64)hi << 32) | lo;
}

// ---------------------------------------------------------------------------
// Kernel 3: popcount conv, 2 pixels x 8 output channels per thread.
// s = 256*nr*nc - 2*(Q - corr). Weights in LDS as ulonglong2 [pos][cw][jj].
// Register pressure management (R2: 256 VGPR; R3: cap-64; R5: NO=16 @128 all
// spilled): launch_bounds(256,2) cap ~128, cw loop NOT unrolled. VGPR=84.
// ---------------------------------------------------------------------------
__global__ __launch_bounds__(256, 2) void conv_kernel(const u64* __restrict__ pk,
                                                      const u64* __restrict__ swg,
                                                      float* __restrict__ y) {
    __shared__ ulonglong2 swl2[9 * 4 * 4];   // u64[pos][cw][j] viewed as pairs
    __shared__ int wpl[9 * 8];               // [pos][j] = sum_cw popc(sw)
    u64* swl = (u64*)swl2;
    int tid = threadIdx.x;
    int o0  = blockIdx.y * NO;
    for (int idx = tid; idx < 288; idx += 256) {   // grid-stride: 288 > 256!
        int pos = idx >> 5, rem = idx & 31, cw = rem >> 3, j = rem & 7;
        swl[idx] = swg[(o0 + j) * 36 + pos * 4 + cw];
    }
    if (tid < 72) {
        int pos = tid >> 3, j = tid & 7;
        const u64* p = swg + (o0 + j) * 36 + pos * 4;
        wpl[tid] = __popcll(p[0]) + __popcll(p[1]) + __popcll(p[2]) + __popcll(p[3]);
    }
    __syncthreads();

    int gs = blockIdx.x * 256 + tid;       // 0..50175 (grid.x = 196, exact)
    int n  = gs / 1568;                    // 56*28
    int r2 = gs - n * 1568;
    int h  = r2 / 28;
    int wg = r2 - h * 28;
    int w0 = wg * 2;

    int Q[WP][NO];
#pragma unroll
    for (int p = 0; p < WP; ++p)
#pragma unroll
        for (int j = 0; j < NO; ++j) Q[p][j] = 0;

    const u64* pkn = pk + (size_t)n * 4 * 3136;

#pragma unroll 1
    for (int cw = 0; cw < 4; ++cw) {
#pragma unroll
        for (int r = 0; r < 3; ++r) {
            int hh = h - 1 + r;
            int hc = hh < 0 ? 0 : (hh > 55 ? 55 : hh);
            const u64* rowp = pkn + ((size_t)cw * 56 + hc) * 56;
            bool hv = (hh >= 0) && (hh <= 55);
            u64 win[4];
#pragma unroll
            for (int c4 = 0; c4 < 4; ++c4) {
                int cc  = w0 - 1 + c4;
                int ccc = cc < 0 ? 0 : (cc > 55 ? 55 : cc);
                u64 v   = rowp[ccc];
                bool ok = hv && (cc >= 0) && (cc <= 55);
                win[c4] = ok ? v : 0ull;
            }
#pragma unroll
            for (int dw = 0; dw < 3; ++dw) {
#pragma unroll
                for (int jj = 0; jj < 4; ++jj) {
                    ulonglong2 wv = swl2[((r * 3 + dw) * 4 + cw) * 4 + jj];
                    Q[0][2 * jj]     += __popcll(win[dw]     ^ wv.x);
                    Q[1][2 * jj]     += __popcll(win[dw + 1] ^ wv.x);
                    Q[0][2 * jj + 1] += __popcll(win[dw]     ^ wv.y);
                    Q[1][2 * jj + 1] += __popcll(win[dw + 1] ^ wv.y);
                }
            }
        }
    }

    // Border corrections: subtract popc(sw) of zeroed (invalid) window words.
    if (h == 0 || h == 55 || w0 == 0 || w0 == 54) {
#pragma unroll
        for (int j = 0; j < NO; ++j) {
            int crow = 0;
            if (h == 0)  crow += wpl[0 * 8 + j] + wpl[1 * 8 + j] + wpl[2 * 8 + j];
            if (h == 55) crow += wpl[6 * 8 + j] + wpl[7 * 8 + j] + wpl[8 * 8 + j];
#pragma unroll
            for (int p = 0; p < WP; ++p) {
                int w = w0 + p;
                int c = crow;
                if (w == 0) {
                    if (h > 0)  c += wpl[0 * 8 + j];
                    c += wpl[3 * 8 + j];
                    if (h < 55) c += wpl[6 * 8 + j];
                }
                if (w == 55) {
                    if (h > 0)  c += wpl[2 * 8 + j];
                    c += wpl[5 * 8 + j];
                    if (h < 55) c += wpl[8 * 8 + j];
                }
                Q[p][j] -= c;
            }
        }
    }

    int nr = 3 - (h == 0) - (h == 55);
    int base[WP];
#pragma unroll
    for (int p = 0; p < WP; ++p) {
        int w  = w0 + p;
        int nc = 3 - (w == 0) - (w == 55);
        base[p] = 256 * nr * nc;
    }

    float* yb = y + (size_t)(n * 256 + o0) * 3136 + h * 56 + w0;
#pragma unroll
    for (int j = 0; j < NO; ++j) {
        float2 v;
        v.x = (float)(base[0] - 2 * Q[0][j]);
        v.y = (float)(base[1] - 2 * Q[1][j]);
        *(float2*)(yb + (size_t)j * 3136) = v;
    }
}

extern "C" void kernel_launch(void* const* d_in, const int* in_sizes, int n_in,
                              void* d_out, int out_size, void* d_ws, size_t ws_size,
                              hipStream_t stream) {
    const float* x  = (const float*)d_in[0];
    // d_in[1] (latent weight) is unused in the forward value (STE).
    const float* cb = (const float*)d_in[2];
    const int* enc  = (const int*)d_in[3];
    float* y        = (float*)d_out;

    u64* swg = (u64*)d_ws;
    u64* pk  = (u64*)((char*)d_ws + PK_OFF);

    hipLaunchKernelGGL(pack_w_kernel, dim3(2304), dim3(256), 0, stream, enc, cb, swg);
    hipLaunchKernelGGL(pack_x_kernel, dim3(1792), dim3(256), 0, stream, x, pk);
    hipLaunchKernelGGL(conv_kernel, dim3(196, 32), dim3(256), 0, stream, pk, swg, y);
}